// Round 17
// baseline (581.533 us; speedup 1.0000x reference)
//
#include <hip/hip_runtime.h>
#include <hip/hip_bf16.h>

#define DIM 128
#define GATE_EPS 1e-6f
#define BN_EPS 1e-5f
#define AGG_BLOCKS 2048

typedef unsigned int u32;
typedef unsigned short u16;

__device__ __forceinline__ float bflo(u32 u) { return __uint_as_float(u << 16); }
__device__ __forceinline__ float bfhi(u32 u) { return __uint_as_float(u & 0xffff0000u); }

__device__ __forceinline__ u16 f2bf(float f) {
    u32 u = __float_as_uint(f);
    u32 r = (u + 0x7fffu + ((u >> 16) & 1u)) >> 16;  // RNE
    return (u16)r;
}

// scalar dtype-adaptive load
__device__ __forceinline__ float loadF(const void* p, size_t i, int bf) {
    if (bf) return __uint_as_float(((u32)((const u16*)p)[i]) << 16);
    return ((const float*)p)[i];
}

// ---------------------------------------------------------------------------
// K0: detect device float dtype (verbatim from passing rounds).
// ---------------------------------------------------------------------------
__global__ void detect_dtype(const void* __restrict__ h, int* __restrict__ flag) {
    if (threadIdx.x == 0 && blockIdx.x == 0) {
        const u16* us = (const u16*)h;
        int cnt = 0;
        for (int i = 0; i < 256; ++i) {
            int e8 = (us[2 * i] >> 7) & 0xFF;
            if (e8 >= 0x60 && e8 <= 0x8F) ++cnt;
        }
        *flag = (cnt >= 192) ? 1 : 0;
    }
}

// ---------------------------------------------------------------------------
// K1: fused 4-projection GEMM (y<4) + CSR scatter (y==4) + e-copy (y==5).
// ONE CHANGE vs R16: e-copy moved here from the aggregate dispatch — its
// pure-HBM work hides under proj's compute-bound phase (HBM idle there),
// and the aggregate's scattered gather no longer competes with it.
// ---------------------------------------------------------------------------
__global__ __launch_bounds__(256) void proj_gemm(
    const void* __restrict__ h,
    const void* __restrict__ W0, const void* __restrict__ b0,
    const void* __restrict__ W1, const void* __restrict__ b1,
    const void* __restrict__ W2, const void* __restrict__ b2,
    const void* __restrict__ W3, const void* __restrict__ b3,
    float* __restrict__ oAh, u32* __restrict__ oDB, u32* __restrict__ oEhb,
    int N, const int* __restrict__ flagp,
    const int* __restrict__ src, const int* __restrict__ dst,
    int* __restrict__ cursor, int* __restrict__ esrc, int E,
    const void* __restrict__ e, void* __restrict__ dout,
    size_t nd, size_t ecount)
{
    if (blockIdx.y == 4) {
        // ---- scatter branch (verbatim R14, grid-stride) ----
        int stride = gridDim.x * 256;
        for (int ei = blockIdx.x * 256 + threadIdx.x; ei < E; ei += stride) {
            int pos = atomicAdd(&cursor[dst[ei]], 1);
            esrc[pos] = src[ei];
        }
        return;
    }
    if (blockIdx.y == 5) {
        // ---- e-copy branch (verbatim R14 body, grid-stride over x-blocks) ----
        int bf = *flagp;
        size_t esz = bf ? 2 : 4;
        const uint4* s = (const uint4*)e;
        uint4* d = (uint4*)((char*)dout + nd * esz);
        size_t n16 = (ecount * esz) / 16;
        size_t idx = (size_t)blockIdx.x * 256 + threadIdx.x;
        size_t stride = (size_t)gridDim.x * 256;
        for (size_t i = idx; i < n16; i += stride) d[i] = s[i];
        return;
    }

    const void* W; const void* bias;
    switch (blockIdx.y) {
        case 0:  W = W0; bias = b0; break;
        case 1:  W = W1; bias = b1; break;
        case 2:  W = W2; bias = b2; break;
        default: W = W3; bias = b3; break;
    }
    const int bf = *flagp;

    __shared__ float Hs[64][DIM + 4];
    __shared__ float Ws[16][DIM];

    const int t  = threadIdx.x;
    const int m0 = blockIdx.x * 64;

    if (bf) {
        for (int f = t; f < 1024; f += 256) {
            int r = f >> 4, c8 = f & 15;
            int gr = m0 + r;
            uint4 v = make_uint4(0u, 0u, 0u, 0u);
            if (gr < N) v = ((const uint4*)h)[(size_t)gr * 16 + c8];
            float* p = &Hs[r][c8 * 8];
            p[0] = bflo(v.x); p[1] = bfhi(v.x);
            p[2] = bflo(v.y); p[3] = bfhi(v.y);
            p[4] = bflo(v.z); p[5] = bfhi(v.z);
            p[6] = bflo(v.w); p[7] = bfhi(v.w);
        }
    } else {
        for (int f = t; f < 2048; f += 256) {
            int r = f >> 5, c4 = f & 31;
            int gr = m0 + r;
            float4 v = make_float4(0.f, 0.f, 0.f, 0.f);
            if (gr < N) v = ((const float4*)h)[(size_t)gr * 32 + c4];
            float* p = &Hs[r][c4 * 4];
            p[0] = v.x; p[1] = v.y; p[2] = v.z; p[3] = v.w;
        }
    }

    const int cg = t & 31;
    const int rg = t >> 5;

    float acc[8][4];
    #pragma unroll
    for (int i = 0; i < 8; ++i)
        #pragma unroll
        for (int j = 0; j < 4; ++j) acc[i][j] = 0.f;

    for (int kc = 0; kc < DIM; kc += 16) {
        __syncthreads();
        if (bf) {
            int r = t >> 4, c8 = t & 15;
            uint4 v = ((const uint4*)W)[(size_t)(kc + r) * 16 + c8];
            float* p = &Ws[r][c8 * 8];
            p[0] = bflo(v.x); p[1] = bfhi(v.x);
            p[2] = bflo(v.y); p[3] = bfhi(v.y);
            p[4] = bflo(v.z); p[5] = bfhi(v.z);
            p[6] = bflo(v.w); p[7] = bfhi(v.w);
        } else {
            for (int f = t; f < 512; f += 256) {
                int r = f >> 5, c4 = f & 31;
                float4 v = ((const float4*)W)[(size_t)(kc + r) * 32 + c4];
                float* p = &Ws[r][c4 * 4];
                p[0] = v.x; p[1] = v.y; p[2] = v.z; p[3] = v.w;
            }
        }
        __syncthreads();
        #pragma unroll
        for (int kk = 0; kk < 16; ++kk) {
            float4 w = *((const float4*)&Ws[kk][cg * 4]);
            #pragma unroll
            for (int i = 0; i < 8; ++i) {
                float hv = Hs[rg * 8 + i][kc + kk];
                acc[i][0] += hv * w.x;
                acc[i][1] += hv * w.y;
                acc[i][2] += hv * w.z;
                acc[i][3] += hv * w.w;
            }
        }
    }

    float bv[4];
    #pragma unroll
    for (int j = 0; j < 4; ++j) bv[j] = loadF(bias, cg * 4 + j, bf);

    const int y = blockIdx.y;
    #pragma unroll
    for (int i = 0; i < 8; ++i) {
        int gr = m0 + rg * 8 + i;
        if (gr < N) {
            float v0 = acc[i][0] + bv[0];
            float v1 = acc[i][1] + bv[1];
            float v2 = acc[i][2] + bv[2];
            float v3 = acc[i][3] + bv[3];
            if (y == 0) {
                ((float4*)oAh)[(size_t)gr * 32 + cg] = make_float4(v0, v1, v2, v3);
            } else {
                uint2 p;
                p.x = (u32)f2bf(v0) | ((u32)f2bf(v1) << 16);
                p.y = (u32)f2bf(v2) | ((u32)f2bf(v3) << 16);
                size_t idx;
                if (y == 1)      idx = (size_t)gr * 64 + 32 + cg;  // Bh half of DB
                else if (y == 2) idx = (size_t)gr * 64 + cg;       // Dh half of DB
                else             idx = (size_t)gr * 32 + cg;       // Ehb
                u32* base = (y == 3) ? oEhb : oDB;
                ((uint2*)base)[idx] = p;
            }
        }
    }
}

// ---------------------------------------------------------------------------
// CSR build (verbatim from passing rounds).
// ---------------------------------------------------------------------------
__global__ __launch_bounds__(256) void k_hist(const int* __restrict__ dst,
                                              int* __restrict__ deg, int E)
{
    int e = blockIdx.x * 256 + threadIdx.x;
    if (e < E) atomicAdd(&deg[dst[e]], 1);
}

__global__ __launch_bounds__(256) void k_scan1(const int* __restrict__ deg,
                                               int* __restrict__ rowstart,
                                               int* __restrict__ part, int N)
{
    __shared__ int s[256];
    int t = threadIdx.x;
    int i = blockIdx.x * 256 + t;
    int d = (i < N) ? deg[i] : 0;
    s[t] = d;
    __syncthreads();
    for (int off = 1; off < 256; off <<= 1) {
        int v = (t >= off) ? s[t - off] : 0;
        __syncthreads();
        s[t] += v;
        __syncthreads();
    }
    if (i < N) rowstart[i] = s[t] - d;
    if (t == 255) part[blockIdx.x] = s[255];
}

__global__ void k_scan2(int* __restrict__ part, int nb)
{
    __shared__ int s[256];
    int t = threadIdx.x;
    int d = (t < nb) ? part[t] : 0;
    s[t] = d;
    __syncthreads();
    for (int off = 1; off < 256; off <<= 1) {
        int v = (t >= off) ? s[t - off] : 0;
        __syncthreads();
        s[t] += v;
        __syncthreads();
    }
    if (t < nb) part[t] = s[t] - d;
}

__global__ __launch_bounds__(256) void k_scan3(int* __restrict__ rowstart,
                                               int* __restrict__ cursor,
                                               const int* __restrict__ part,
                                               int N, int E)
{
    int i = blockIdx.x * 256 + threadIdx.x;
    if (i < N) {
        int v = rowstart[i] + part[blockIdx.x];
        rowstart[i] = v;
        cursor[i] = v;
    }
    if (i == 0) rowstart[N] = E;
}

// ---------------------------------------------------------------------------
// K3: pure CSR aggregation (R13 mapping: abid = blockIdx.x, 2048 blocks;
// body verbatim R16 minus the copy branch).
// ---------------------------------------------------------------------------
__global__ __launch_bounds__(256) void k_aggregate(
    const float* __restrict__ Ah, const u32* __restrict__ DB,
    const u32* __restrict__ Ehb,
    const int* __restrict__ rowstart, const int* __restrict__ esrc,
    float* __restrict__ hnew, float* __restrict__ gsum, float* __restrict__ gsq,
    int N)
{
    int t = threadIdx.x;
    int lane = t & 63;
    int wv = t >> 6;
    int nquads = (N + 3) >> 2;

    float lsum0 = 0.f, lsum1 = 0.f, lsq0 = 0.f, lsq1 = 0.f;
    for (int q = blockIdx.x; q < nquads; q += AGG_BLOCKS) {
        int n = q * 4 + wv;
        if (n < N) {
            u32 ehp = Ehb[(size_t)n * 64 + lane];
            float eh0 = bflo(ehp), eh1 = bfhi(ehp);
            float2 ahp = ((const float2*)Ah)[(size_t)n * 64 + lane];
            float num0 = 0.f, den0 = 0.f, num1 = 0.f, den1 = 0.f;
            int beg = rowstart[n], end = rowstart[n + 1];
            int k = beg;
            for (; k + 4 <= end; k += 4) {
                int s0 = esrc[k], s1 = esrc[k + 1], s2 = esrc[k + 2], s3 = esrc[k + 3];
                u32 dhA = DB[(size_t)s0 * 128 + lane];
                u32 bhA = DB[(size_t)s0 * 128 + 64 + lane];
                u32 dhB = DB[(size_t)s1 * 128 + lane];
                u32 bhB = DB[(size_t)s1 * 128 + 64 + lane];
                u32 dhC = DB[(size_t)s2 * 128 + lane];
                u32 bhC = DB[(size_t)s2 * 128 + 64 + lane];
                u32 dhD = DB[(size_t)s3 * 128 + lane];
                u32 bhD = DB[(size_t)s3 * 128 + 64 + lane];
                float sA0 = 1.f / (1.f + __expf(-(bflo(dhA) + eh0)));
                float sA1 = 1.f / (1.f + __expf(-(bfhi(dhA) + eh1)));
                float sB0 = 1.f / (1.f + __expf(-(bflo(dhB) + eh0)));
                float sB1 = 1.f / (1.f + __expf(-(bfhi(dhB) + eh1)));
                float sC0 = 1.f / (1.f + __expf(-(bflo(dhC) + eh0)));
                float sC1 = 1.f / (1.f + __expf(-(bfhi(dhC) + eh1)));
                float sD0 = 1.f / (1.f + __expf(-(bflo(dhD) + eh0)));
                float sD1 = 1.f / (1.f + __expf(-(bfhi(dhD) + eh1)));
                num0 = fmaf(sA0, bflo(bhA), num0); den0 += sA0;
                num1 = fmaf(sA1, bfhi(bhA), num1); den1 += sA1;
                num0 = fmaf(sB0, bflo(bhB), num0); den0 += sB0;
                num1 = fmaf(sB1, bfhi(bhB), num1); den1 += sB1;
                num0 = fmaf(sC0, bflo(bhC), num0); den0 += sC0;
                num1 = fmaf(sC1, bfhi(bhC), num1); den1 += sC1;
                num0 = fmaf(sD0, bflo(bhD), num0); den0 += sD0;
                num1 = fmaf(sD1, bfhi(bhD), num1); den1 += sD1;
            }
            for (; k < end; ++k) {
                int s0 = esrc[k];
                u32 dh0 = DB[(size_t)s0 * 128 + lane];
                u32 bh0 = DB[(size_t)s0 * 128 + 64 + lane];
                float sa0 = 1.f / (1.f + __expf(-(bflo(dh0) + eh0)));
                float sa1 = 1.f / (1.f + __expf(-(bfhi(dh0) + eh1)));
                num0 = fmaf(sa0, bflo(bh0), num0); den0 += sa0;
                num1 = fmaf(sa1, bfhi(bh0), num1); den1 += sa1;
            }
            float x0 = ahp.x + num0 / (den0 + GATE_EPS);
            float x1 = ahp.y + num1 / (den1 + GATE_EPS);
            ((float2*)hnew)[(size_t)n * 64 + lane] = make_float2(x0, x1);
            lsum0 += x0; lsq0 += x0 * x0;
            lsum1 += x1; lsq1 += x1 * x1;
        }
    }
    __shared__ float S0[256], S1[256], Q0[256], Q1[256];
    S0[t] = lsum0; S1[t] = lsum1; Q0[t] = lsq0; Q1[t] = lsq1;
    __syncthreads();
    if (t < 64) {
        float s0 = S0[t] + S0[t + 64] + S0[t + 128] + S0[t + 192];
        float s1 = S1[t] + S1[t + 64] + S1[t + 128] + S1[t + 192];
        float q0 = Q0[t] + Q0[t + 64] + Q0[t + 128] + Q0[t + 192];
        float q1 = Q1[t] + Q1[t + 64] + Q1[t + 128] + Q1[t + 192];
        atomicAdd(&gsum[2 * t],     s0);
        atomicAdd(&gsum[2 * t + 1], s1);
        atomicAdd(&gsq[2 * t],      q0);
        atomicAdd(&gsq[2 * t + 1],  q1);
    }
}

// ---------------------------------------------------------------------------
// K4: finalize BN stats (verbatim from passing rounds).
// ---------------------------------------------------------------------------
__global__ void bn_finalize(const float* __restrict__ gsum, const float* __restrict__ gsq,
                            const void* __restrict__ gamma, const void* __restrict__ beta,
                            float* __restrict__ scale, float* __restrict__ shift,
                            int N, const int* __restrict__ flagp)
{
    int c = threadIdx.x;
    int bf = *flagp;
    if (c < DIM) {
        float invn = 1.f / (float)N;
        float mean = gsum[c] * invn;
        float var  = fmaxf(gsq[c] * invn - mean * mean, 0.f);
        float g = loadF(gamma, c, bf);
        float b = loadF(beta, c, bf);
        float sc = rsqrtf(var + BN_EPS) * g;
        scale[c] = sc;
        shift[c] = b - mean * sc;
    }
}

// ---------------------------------------------------------------------------
// K5: y = relu(x*scale + shift), vectorized (verbatim R16).
// ---------------------------------------------------------------------------
__global__ __launch_bounds__(256) void bn_apply(
    const float* __restrict__ hnew, const float* __restrict__ scale,
    const float* __restrict__ shift, void* __restrict__ outh,
    int nvec, const int* __restrict__ flagp)
{
    __shared__ float s_sc[DIM], s_sh[DIM];
    int t = threadIdx.x;
    if (t < DIM) { s_sc[t] = scale[t]; s_sh[t] = shift[t]; }
    __syncthreads();
    int bf = *flagp;

    int idx = blockIdx.x * 256 + t;
    int stride = gridDim.x * 256;
    for (int i = idx; i < nvec; i += stride) {
        float4 v = ((const float4*)hnew)[i];
        int c = (i & 31) * 4;
        float a0 = fmaxf(0.f, v.x * s_sc[c + 0] + s_sh[c + 0]);
        float a1 = fmaxf(0.f, v.y * s_sc[c + 1] + s_sh[c + 1]);
        float a2 = fmaxf(0.f, v.z * s_sc[c + 2] + s_sh[c + 2]);
        float a3 = fmaxf(0.f, v.w * s_sc[c + 3] + s_sh[c + 3]);
        if (bf) {
            uint2 o;
            o.x = (u32)f2bf(a0) | ((u32)f2bf(a1) << 16);
            o.y = (u32)f2bf(a2) | ((u32)f2bf(a3) << 16);
            ((uint2*)outh)[i] = o;
        } else {
            ((float4*)outh)[i] = make_float4(a0, a1, a2, a3);
        }
    }
}

// ---------------------------------------------------------------------------
extern "C" void kernel_launch(void* const* d_in, const int* in_sizes, int n_in,
                              void* d_out, int out_size, void* d_ws, size_t ws_size,
                              hipStream_t stream)
{
    const void* h     = d_in[0];
    const void* e     = d_in[1];
    const int*  src   = (const int*)d_in[2];
    const int*  dst   = (const int*)d_in[3];
    const void* Wa    = d_in[4];
    const void* ba    = d_in[5];
    const void* Wb    = d_in[6];
    const void* bb    = d_in[7];
    const void* Wd    = d_in[8];
    const void* bd    = d_in[9];
    const void* We    = d_in[10];
    const void* be    = d_in[11];
    const void* gamma = d_in[12];
    const void* beta  = d_in[13];

    const int N = in_sizes[0] / DIM;        // 50000
    const int E = in_sizes[2];              // 800000
    const size_t nd = (size_t)N * DIM;
    const size_t ecount = (size_t)E * DIM;

    float* ws    = (float*)d_ws;
    float* Ah    = ws;                         // nd f32
    float* hnew  = ws + nd;                    // nd f32
    u32*   DB    = (u32*)(ws + 2 * nd);        // N*128 u32 (Dh|Bh halves)
    u32*   Ehb   = (u32*)(ws + 3 * nd);        // N*64 u32 (Eh bf16 pairs)
    float* gsum  = ws + 3 * nd + nd / 2;       // 128
    float* gsq   = gsum + DIM;                 // 128
    float* scale = gsum + 2 * DIM;             // 128
    float* shift = gsum + 3 * DIM;             // 128
    int*   flag  = (int*)(gsum + 4 * DIM);     // [0]=dtype
    int*   deg      = flag + 64;               // N
    int*   rowstart = deg + N;                 // N+1
    int*   cursor   = rowstart + N + 1;        // N
    int*   part     = cursor + N;              // 256
    int*   esrc     = part + 256;              // E

    // zero BN stats + flag area, then detect_dtype writes flag[0].
    hipMemsetAsync(gsum, 0, (4 * DIM + 64) * sizeof(float), stream);
    hipMemsetAsync(deg, 0, (size_t)N * sizeof(int), stream);

    detect_dtype<<<1, 64, 0, stream>>>(h, flag);

    const int nbE = (E + 255) / 256;
    const int nbN = (N + 255) / 256;

    k_hist<<<nbE, 256, 0, stream>>>(dst, deg, E);
    k_scan1<<<nbN, 256, 0, stream>>>(deg, rowstart, part, N);
    k_scan2<<<1, 256, 0, stream>>>(part, nbN);
    k_scan3<<<nbN, 256, 0, stream>>>(rowstart, cursor, part, N, E);

    // fused: proj (y<4) + scatter (y==4) + e-copy (y==5)
    dim3 g1((N + 63) / 64, 6);
    proj_gemm<<<g1, 256, 0, stream>>>(h, Wa, ba, Wb, bb, Wd, bd, We, be,
                                      Ah, DB, Ehb, N, flag,
                                      src, dst, cursor, esrc, E,
                                      e, d_out, nd, ecount);

    // pure aggregate (2048 blocks)
    k_aggregate<<<AGG_BLOCKS, 256, 0, stream>>>(
        Ah, DB, Ehb, rowstart, esrc, hnew, gsum, gsq, N);

    bn_finalize<<<1, 128, 0, stream>>>(gsum, gsq, gamma, beta, scale, shift, N, flag);

    bn_apply<<<2048, 256, 0, stream>>>(hnew, scale, shift, d_out, (int)(nd / 4), flag);
}

// Round 18
// 467.194 us; speedup vs baseline: 1.2447x; 1.2447x over previous
//
#include <hip/hip_runtime.h>
#include <hip/hip_bf16.h>

#define DIM 128
#define GATE_EPS 1e-6f
#define BN_EPS 1e-5f
#define AGG_BLOCKS 2048

typedef unsigned int u32;
typedef unsigned short u16;

__device__ __forceinline__ float bflo(u32 u) { return __uint_as_float(u << 16); }
__device__ __forceinline__ float bfhi(u32 u) { return __uint_as_float(u & 0xffff0000u); }

__device__ __forceinline__ u16 f2bf(float f) {
    u32 u = __float_as_uint(f);
    u32 r = (u + 0x7fffu + ((u >> 16) & 1u)) >> 16;  // RNE
    return (u16)r;
}

// scalar dtype-adaptive load
__device__ __forceinline__ float loadF(const void* p, size_t i, int bf) {
    if (bf) return __uint_as_float(((u32)((const u16*)p)[i]) << 16);
    return ((const float*)p)[i];
}

// two edges of one node: issue 4 gathers, then math
__device__ __forceinline__ void edges2(const u32* __restrict__ DB, int sa, int sb,
                                       int lane, float eh0, float eh1,
                                       float& num0, float& den0,
                                       float& num1, float& den1)
{
    u32 dhA = DB[(size_t)sa * 128 + lane];
    u32 bhA = DB[(size_t)sa * 128 + 64 + lane];
    u32 dhB = DB[(size_t)sb * 128 + lane];
    u32 bhB = DB[(size_t)sb * 128 + 64 + lane];
    float sA0 = 1.f / (1.f + __expf(-(bflo(dhA) + eh0)));
    float sA1 = 1.f / (1.f + __expf(-(bfhi(dhA) + eh1)));
    float sB0 = 1.f / (1.f + __expf(-(bflo(dhB) + eh0)));
    float sB1 = 1.f / (1.f + __expf(-(bfhi(dhB) + eh1)));
    num0 = fmaf(sA0, bflo(bhA), num0); den0 += sA0;
    num1 = fmaf(sA1, bfhi(bhA), num1); den1 += sA1;
    num0 = fmaf(sB0, bflo(bhB), num0); den0 += sB0;
    num1 = fmaf(sB1, bfhi(bhB), num1); den1 += sB1;
}

// one edge of one node
__device__ __forceinline__ void edge1(const u32* __restrict__ DB, int sa,
                                      int lane, float eh0, float eh1,
                                      float& num0, float& den0,
                                      float& num1, float& den1)
{
    u32 dhA = DB[(size_t)sa * 128 + lane];
    u32 bhA = DB[(size_t)sa * 128 + 64 + lane];
    float sA0 = 1.f / (1.f + __expf(-(bflo(dhA) + eh0)));
    float sA1 = 1.f / (1.f + __expf(-(bfhi(dhA) + eh1)));
    num0 = fmaf(sA0, bflo(bhA), num0); den0 += sA0;
    num1 = fmaf(sA1, bfhi(bhA), num1); den1 += sA1;
}

// ---------------------------------------------------------------------------
// K0: detect device float dtype (verbatim from passing rounds).
// ---------------------------------------------------------------------------
__global__ void detect_dtype(const void* __restrict__ h, int* __restrict__ flag) {
    if (threadIdx.x == 0 && blockIdx.x == 0) {
        const u16* us = (const u16*)h;
        int cnt = 0;
        for (int i = 0; i < 256; ++i) {
            int e8 = (us[2 * i] >> 7) & 0xFF;
            if (e8 >= 0x60 && e8 <= 0x8F) ++cnt;
        }
        *flag = (cnt >= 192) ? 1 : 0;
    }
}

// ---------------------------------------------------------------------------
// K1: fused 4-projection GEMM + CSR scatter on grid.y==4 (verbatim R16).
// ---------------------------------------------------------------------------
__global__ __launch_bounds__(256) void proj_gemm(
    const void* __restrict__ h,
    const void* __restrict__ W0, const void* __restrict__ b0,
    const void* __restrict__ W1, const void* __restrict__ b1,
    const void* __restrict__ W2, const void* __restrict__ b2,
    const void* __restrict__ W3, const void* __restrict__ b3,
    float* __restrict__ oAh, u32* __restrict__ oDB, u32* __restrict__ oEhb,
    int N, const int* __restrict__ flagp,
    const int* __restrict__ src, const int* __restrict__ dst,
    int* __restrict__ cursor, int* __restrict__ esrc, int E)
{
    if (blockIdx.y == 4) {
        int stride = gridDim.x * 256;
        for (int e = blockIdx.x * 256 + threadIdx.x; e < E; e += stride) {
            int pos = atomicAdd(&cursor[dst[e]], 1);
            esrc[pos] = src[e];
        }
        return;
    }

    const void* W; const void* bias;
    switch (blockIdx.y) {
        case 0:  W = W0; bias = b0; break;
        case 1:  W = W1; bias = b1; break;
        case 2:  W = W2; bias = b2; break;
        default: W = W3; bias = b3; break;
    }
    const int bf = *flagp;

    __shared__ float Hs[64][DIM + 4];
    __shared__ float Ws[16][DIM];

    const int t  = threadIdx.x;
    const int m0 = blockIdx.x * 64;

    if (bf) {
        for (int f = t; f < 1024; f += 256) {
            int r = f >> 4, c8 = f & 15;
            int gr = m0 + r;
            uint4 v = make_uint4(0u, 0u, 0u, 0u);
            if (gr < N) v = ((const uint4*)h)[(size_t)gr * 16 + c8];
            float* p = &Hs[r][c8 * 8];
            p[0] = bflo(v.x); p[1] = bfhi(v.x);
            p[2] = bflo(v.y); p[3] = bfhi(v.y);
            p[4] = bflo(v.z); p[5] = bfhi(v.z);
            p[6] = bflo(v.w); p[7] = bfhi(v.w);
        }
    } else {
        for (int f = t; f < 2048; f += 256) {
            int r = f >> 5, c4 = f & 31;
            int gr = m0 + r;
            float4 v = make_float4(0.f, 0.f, 0.f, 0.f);
            if (gr < N) v = ((const float4*)h)[(size_t)gr * 32 + c4];
            float* p = &Hs[r][c4 * 4];
            p[0] = v.x; p[1] = v.y; p[2] = v.z; p[3] = v.w;
        }
    }

    const int cg = t & 31;
    const int rg = t >> 5;

    float acc[8][4];
    #pragma unroll
    for (int i = 0; i < 8; ++i)
        #pragma unroll
        for (int j = 0; j < 4; ++j) acc[i][j] = 0.f;

    for (int kc = 0; kc < DIM; kc += 16) {
        __syncthreads();
        if (bf) {
            int r = t >> 4, c8 = t & 15;
            uint4 v = ((const uint4*)W)[(size_t)(kc + r) * 16 + c8];
            float* p = &Ws[r][c8 * 8];
            p[0] = bflo(v.x); p[1] = bfhi(v.x);
            p[2] = bflo(v.y); p[3] = bfhi(v.y);
            p[4] = bflo(v.z); p[5] = bfhi(v.z);
            p[6] = bflo(v.w); p[7] = bfhi(v.w);
        } else {
            for (int f = t; f < 512; f += 256) {
                int r = f >> 5, c4 = f & 31;
                float4 v = ((const float4*)W)[(size_t)(kc + r) * 32 + c4];
                float* p = &Ws[r][c4 * 4];
                p[0] = v.x; p[1] = v.y; p[2] = v.z; p[3] = v.w;
            }
        }
        __syncthreads();
        #pragma unroll
        for (int kk = 0; kk < 16; ++kk) {
            float4 w = *((const float4*)&Ws[kk][cg * 4]);
            #pragma unroll
            for (int i = 0; i < 8; ++i) {
                float hv = Hs[rg * 8 + i][kc + kk];
                acc[i][0] += hv * w.x;
                acc[i][1] += hv * w.y;
                acc[i][2] += hv * w.z;
                acc[i][3] += hv * w.w;
            }
        }
    }

    float bv[4];
    #pragma unroll
    for (int j = 0; j < 4; ++j) bv[j] = loadF(bias, cg * 4 + j, bf);

    const int y = blockIdx.y;
    #pragma unroll
    for (int i = 0; i < 8; ++i) {
        int gr = m0 + rg * 8 + i;
        if (gr < N) {
            float v0 = acc[i][0] + bv[0];
            float v1 = acc[i][1] + bv[1];
            float v2 = acc[i][2] + bv[2];
            float v3 = acc[i][3] + bv[3];
            if (y == 0) {
                ((float4*)oAh)[(size_t)gr * 32 + cg] = make_float4(v0, v1, v2, v3);
            } else {
                uint2 p;
                p.x = (u32)f2bf(v0) | ((u32)f2bf(v1) << 16);
                p.y = (u32)f2bf(v2) | ((u32)f2bf(v3) << 16);
                size_t idx;
                if (y == 1)      idx = (size_t)gr * 64 + 32 + cg;  // Bh half of DB
                else if (y == 2) idx = (size_t)gr * 64 + cg;       // Dh half of DB
                else             idx = (size_t)gr * 32 + cg;       // Ehb
                u32* base = (y == 3) ? oEhb : oDB;
                ((uint2*)base)[idx] = p;
            }
        }
    }
}

// ---------------------------------------------------------------------------
// CSR build (verbatim from passing rounds).
// ---------------------------------------------------------------------------
__global__ __launch_bounds__(256) void k_hist(const int* __restrict__ dst,
                                              int* __restrict__ deg, int E)
{
    int e = blockIdx.x * 256 + threadIdx.x;
    if (e < E) atomicAdd(&deg[dst[e]], 1);
}

__global__ __launch_bounds__(256) void k_scan1(const int* __restrict__ deg,
                                               int* __restrict__ rowstart,
                                               int* __restrict__ part, int N)
{
    __shared__ int s[256];
    int t = threadIdx.x;
    int i = blockIdx.x * 256 + t;
    int d = (i < N) ? deg[i] : 0;
    s[t] = d;
    __syncthreads();
    for (int off = 1; off < 256; off <<= 1) {
        int v = (t >= off) ? s[t - off] : 0;
        __syncthreads();
        s[t] += v;
        __syncthreads();
    }
    if (i < N) rowstart[i] = s[t] - d;
    if (t == 255) part[blockIdx.x] = s[255];
}

__global__ void k_scan2(int* __restrict__ part, int nb)
{
    __shared__ int s[256];
    int t = threadIdx.x;
    int d = (t < nb) ? part[t] : 0;
    s[t] = d;
    __syncthreads();
    for (int off = 1; off < 256; off <<= 1) {
        int v = (t >= off) ? s[t - off] : 0;
        __syncthreads();
        s[t] += v;
        __syncthreads();
    }
    if (t < nb) part[t] = s[t] - d;
}

__global__ __launch_bounds__(256) void k_scan3(int* __restrict__ rowstart,
                                               int* __restrict__ cursor,
                                               const int* __restrict__ part,
                                               int N, int E)
{
    int i = blockIdx.x * 256 + threadIdx.x;
    if (i < N) {
        int v = rowstart[i] + part[blockIdx.x];
        rowstart[i] = v;
        cursor[i] = v;
    }
    if (i == 0) rowstart[N] = E;
}

// ---------------------------------------------------------------------------
// K3: fused aggregate + e-copy, interleaved roles (R16 structure).
// ONE CHANGE: each wave processes TWO nodes concurrently (joint 4+4 edge
// unroll = 16 outstanding gathers vs 8) to deepen MLP in the latency-bound
// gather loop. Block covers 8 nodes (4 waves x 2).
// ---------------------------------------------------------------------------
__global__ __launch_bounds__(256) void k_aggregate(
    const float* __restrict__ Ah, const u32* __restrict__ DB,
    const u32* __restrict__ Ehb,
    const int* __restrict__ rowstart, const int* __restrict__ esrc,
    float* __restrict__ hnew, float* __restrict__ gsum, float* __restrict__ gsq,
    int N,
    const void* __restrict__ e, void* __restrict__ dout,
    size_t nd, size_t ecount, const int* __restrict__ flagp)
{
    int t = threadIdx.x;
    int bid = blockIdx.x;
    int r3 = bid % 3;

    if (r3 == 2) {
        int bf = *flagp;
        size_t esz = bf ? 2 : 4;
        const uint4* s = (const uint4*)e;
        uint4* d = (uint4*)((char*)dout + nd * esz);
        size_t n16 = (ecount * esz) / 16;
        size_t cb = (size_t)(gridDim.x / 3);
        size_t idx = (size_t)(bid / 3) * 256 + t;
        size_t stride = cb * 256;
        for (size_t i = idx; i < n16; i += stride) d[i] = s[i];
        return;
    }

    const int abid = (bid / 3) * 2 + r3;

    int lane = t & 63;
    int wv = t >> 6;
    int noct = (N + 7) >> 3;   // 8 nodes per block

    float lsum0 = 0.f, lsum1 = 0.f, lsq0 = 0.f, lsq1 = 0.f;
    for (int q = abid; q < noct; q += AGG_BLOCKS) {
        int n0 = q * 8 + wv * 2;
        int n1 = n0 + 1;
        bool a0 = (n0 < N), a1 = (n1 < N);

        float e00 = 0.f, e01 = 0.f, e10 = 0.f, e11 = 0.f;
        float2 ah0 = make_float2(0.f, 0.f), ah1 = make_float2(0.f, 0.f);
        int k0 = 0, e0 = 0, k1 = 0, e1 = 0;
        if (a0) {
            u32 p = Ehb[(size_t)n0 * 64 + lane];
            e00 = bflo(p); e01 = bfhi(p);
            ah0 = ((const float2*)Ah)[(size_t)n0 * 64 + lane];
            k0 = rowstart[n0]; e0 = rowstart[n0 + 1];
        }
        if (a1) {
            u32 p = Ehb[(size_t)n1 * 64 + lane];
            e10 = bflo(p); e11 = bfhi(p);
            ah1 = ((const float2*)Ah)[(size_t)n1 * 64 + lane];
            k1 = rowstart[n1]; e1 = rowstart[n1 + 1];
        }

        float n00 = 0.f, d00 = 0.f, n01 = 0.f, d01 = 0.f;  // node0 accum
        float n10 = 0.f, d10 = 0.f, n11 = 0.f, d11 = 0.f;  // node1 accum

        // joint loop: 4 edges of each node per iteration -> 16 loads in flight
        while (k0 + 4 <= e0 && k1 + 4 <= e1) {
            int sA = esrc[k0], sB = esrc[k0 + 1], sC = esrc[k0 + 2], sD = esrc[k0 + 3];
            int sE = esrc[k1], sF = esrc[k1 + 1], sG = esrc[k1 + 2], sH = esrc[k1 + 3];
            edges2(DB, sA, sB, lane, e00, e01, n00, d00, n01, d01);
            edges2(DB, sC, sD, lane, e00, e01, n00, d00, n01, d01);
            edges2(DB, sE, sF, lane, e10, e11, n10, d10, n11, d11);
            edges2(DB, sG, sH, lane, e10, e11, n10, d10, n11, d11);
            k0 += 4; k1 += 4;
        }
        // drain node0
        for (; k0 + 4 <= e0; k0 += 4) {
            int sA = esrc[k0], sB = esrc[k0 + 1], sC = esrc[k0 + 2], sD = esrc[k0 + 3];
            edges2(DB, sA, sB, lane, e00, e01, n00, d00, n01, d01);
            edges2(DB, sC, sD, lane, e00, e01, n00, d00, n01, d01);
        }
        for (; k0 + 2 <= e0; k0 += 2) {
            int sA = esrc[k0], sB = esrc[k0 + 1];
            edges2(DB, sA, sB, lane, e00, e01, n00, d00, n01, d01);
        }
        if (k0 < e0) edge1(DB, esrc[k0], lane, e00, e01, n00, d00, n01, d01);
        // drain node1
        for (; k1 + 4 <= e1; k1 += 4) {
            int sE = esrc[k1], sF = esrc[k1 + 1], sG = esrc[k1 + 2], sH = esrc[k1 + 3];
            edges2(DB, sE, sF, lane, e10, e11, n10, d10, n11, d11);
            edges2(DB, sG, sH, lane, e10, e11, n10, d10, n11, d11);
        }
        for (; k1 + 2 <= e1; k1 += 2) {
            int sE = esrc[k1], sF = esrc[k1 + 1];
            edges2(DB, sE, sF, lane, e10, e11, n10, d10, n11, d11);
        }
        if (k1 < e1) edge1(DB, esrc[k1], lane, e10, e11, n10, d10, n11, d11);

        if (a0) {
            float x0 = ah0.x + n00 / (d00 + GATE_EPS);
            float x1 = ah0.y + n01 / (d01 + GATE_EPS);
            ((float2*)hnew)[(size_t)n0 * 64 + lane] = make_float2(x0, x1);
            lsum0 += x0; lsq0 += x0 * x0;
            lsum1 += x1; lsq1 += x1 * x1;
        }
        if (a1) {
            float x0 = ah1.x + n10 / (d10 + GATE_EPS);
            float x1 = ah1.y + n11 / (d11 + GATE_EPS);
            ((float2*)hnew)[(size_t)n1 * 64 + lane] = make_float2(x0, x1);
            lsum0 += x0; lsq0 += x0 * x0;
            lsum1 += x1; lsq1 += x1 * x1;
        }
    }
    __shared__ float S0[256], S1[256], Q0[256], Q1[256];
    S0[t] = lsum0; S1[t] = lsum1; Q0[t] = lsq0; Q1[t] = lsq1;
    __syncthreads();
    if (t < 64) {
        float s0 = S0[t] + S0[t + 64] + S0[t + 128] + S0[t + 192];
        float s1 = S1[t] + S1[t + 64] + S1[t + 128] + S1[t + 192];
        float q0 = Q0[t] + Q0[t + 64] + Q0[t + 128] + Q0[t + 192];
        float q1 = Q1[t] + Q1[t + 64] + Q1[t + 128] + Q1[t + 192];
        atomicAdd(&gsum[2 * t],     s0);
        atomicAdd(&gsum[2 * t + 1], s1);
        atomicAdd(&gsq[2 * t],      q0);
        atomicAdd(&gsq[2 * t + 1],  q1);
    }
}

// ---------------------------------------------------------------------------
// K4: finalize BN stats (verbatim from passing rounds).
// ---------------------------------------------------------------------------
__global__ void bn_finalize(const float* __restrict__ gsum, const float* __restrict__ gsq,
                            const void* __restrict__ gamma, const void* __restrict__ beta,
                            float* __restrict__ scale, float* __restrict__ shift,
                            int N, const int* __restrict__ flagp)
{
    int c = threadIdx.x;
    int bf = *flagp;
    if (c < DIM) {
        float invn = 1.f / (float)N;
        float mean = gsum[c] * invn;
        float var  = fmaxf(gsq[c] * invn - mean * mean, 0.f);
        float g = loadF(gamma, c, bf);
        float b = loadF(beta, c, bf);
        float sc = rsqrtf(var + BN_EPS) * g;
        scale[c] = sc;
        shift[c] = b - mean * sc;
    }
}

// ---------------------------------------------------------------------------
// K5: y = relu(x*scale + shift), vectorized (verbatim R16).
// ---------------------------------------------------------------------------
__global__ __launch_bounds__(256) void bn_apply(
    const float* __restrict__ hnew, const float* __restrict__ scale,
    const float* __restrict__ shift, void* __restrict__ outh,
    int nvec, const int* __restrict__ flagp)
{
    __shared__ float s_sc[DIM], s_sh[DIM];
    int t = threadIdx.x;
    if (t < DIM) { s_sc[t] = scale[t]; s_sh[t] = shift[t]; }
    __syncthreads();
    int bf = *flagp;

    int idx = blockIdx.x * 256 + t;
    int stride = gridDim.x * 256;
    for (int i = idx; i < nvec; i += stride) {
        float4 v = ((const float4*)hnew)[i];
        int c = (i & 31) * 4;
        float a0 = fmaxf(0.f, v.x * s_sc[c + 0] + s_sh[c + 0]);
        float a1 = fmaxf(0.f, v.y * s_sc[c + 1] + s_sh[c + 1]);
        float a2 = fmaxf(0.f, v.z * s_sc[c + 2] + s_sh[c + 2]);
        float a3 = fmaxf(0.f, v.w * s_sc[c + 3] + s_sh[c + 3]);
        if (bf) {
            uint2 o;
            o.x = (u32)f2bf(a0) | ((u32)f2bf(a1) << 16);
            o.y = (u32)f2bf(a2) | ((u32)f2bf(a3) << 16);
            ((uint2*)outh)[i] = o;
        } else {
            ((float4*)outh)[i] = make_float4(a0, a1, a2, a3);
        }
    }
}

// ---------------------------------------------------------------------------
extern "C" void kernel_launch(void* const* d_in, const int* in_sizes, int n_in,
                              void* d_out, int out_size, void* d_ws, size_t ws_size,
                              hipStream_t stream)
{
    const void* h     = d_in[0];
    const void* e     = d_in[1];
    const int*  src   = (const int*)d_in[2];
    const int*  dst   = (const int*)d_in[3];
    const void* Wa    = d_in[4];
    const void* ba    = d_in[5];
    const void* Wb    = d_in[6];
    const void* bb    = d_in[7];
    const void* Wd    = d_in[8];
    const void* bd    = d_in[9];
    const void* We    = d_in[10];
    const void* be    = d_in[11];
    const void* gamma = d_in[12];
    const void* beta  = d_in[13];

    const int N = in_sizes[0] / DIM;        // 50000
    const int E = in_sizes[2];              // 800000
    const size_t nd = (size_t)N * DIM;
    const size_t ecount = (size_t)E * DIM;

    float* ws    = (float*)d_ws;
    float* Ah    = ws;                         // nd f32
    float* hnew  = ws + nd;                    // nd f32
    u32*   DB    = (u32*)(ws + 2 * nd);        // N*128 u32 (Dh|Bh halves)
    u32*   Ehb   = (u32*)(ws + 3 * nd);        // N*64 u32 (Eh bf16 pairs)
    float* gsum  = ws + 3 * nd + nd / 2;       // 128
    float* gsq   = gsum + DIM;                 // 128
    float* scale = gsum + 2 * DIM;             // 128
    float* shift = gsum + 3 * DIM;             // 128
    int*   flag  = (int*)(gsum + 4 * DIM);     // [0]=dtype
    int*   deg      = flag + 64;               // N
    int*   rowstart = deg + N;                 // N+1
    int*   cursor   = rowstart + N + 1;        // N
    int*   part     = cursor + N;              // 256
    int*   esrc     = part + 256;              // E

    // zero BN stats + flag area, then detect_dtype writes flag[0].
    hipMemsetAsync(gsum, 0, (4 * DIM + 64) * sizeof(float), stream);
    hipMemsetAsync(deg, 0, (size_t)N * sizeof(int), stream);

    detect_dtype<<<1, 64, 0, stream>>>(h, flag);

    const int nbE = (E + 255) / 256;
    const int nbN = (N + 255) / 256;

    k_hist<<<nbE, 256, 0, stream>>>(dst, deg, E);
    k_scan1<<<nbN, 256, 0, stream>>>(deg, rowstart, part, N);
    k_scan2<<<1, 256, 0, stream>>>(part, nbN);
    k_scan3<<<nbN, 256, 0, stream>>>(rowstart, cursor, part, N, E);

    // fused: proj (y<4) + scatter (y==4)
    dim3 g1((N + 63) / 64, 5);
    proj_gemm<<<g1, 256, 0, stream>>>(h, Wa, ba, Wb, bb, Wd, bd, We, be,
                                      Ah, DB, Ehb, N, flag,
                                      src, dst, cursor, esrc, E);

    // fused: aggregate (bid%3 in {0,1}) + e-copy (bid%3 == 2), interleaved
    k_aggregate<<<3072, 256, 0, stream>>>(
        Ah, DB, Ehb, rowstart, esrc, hnew, gsum, gsq, N,
        e, d_out, nd, ecount, flag);

    bn_finalize<<<1, 128, 0, stream>>>(gsum, gsq, gamma, beta, scale, shift, N, flag);

    bn_apply<<<2048, 256, 0, stream>>>(hnew, scale, shift, d_out, (int)(nd / 4), flag);
}

// Round 19
// 456.476 us; speedup vs baseline: 1.2740x; 1.0235x over previous
//
#include <hip/hip_runtime.h>
#include <hip/hip_bf16.h>

#define DIM 128
#define GATE_EPS 1e-6f
#define BN_EPS 1e-5f
#define AGG_BLOCKS 2048

typedef unsigned int u32;
typedef unsigned short u16;

__device__ __forceinline__ float bflo(u32 u) { return __uint_as_float(u << 16); }
__device__ __forceinline__ float bfhi(u32 u) { return __uint_as_float(u & 0xffff0000u); }

__device__ __forceinline__ u16 f2bf(float f) {
    u32 u = __float_as_uint(f);
    u32 r = (u + 0x7fffu + ((u >> 16) & 1u)) >> 16;  // RNE
    return (u16)r;
}

// scalar dtype-adaptive load
__device__ __forceinline__ float loadF(const void* p, size_t i, int bf) {
    if (bf) return __uint_as_float(((u32)((const u16*)p)[i]) << 16);
    return ((const float*)p)[i];
}

// ---------------------------------------------------------------------------
// K0: detect device float dtype (verbatim from passing rounds).
// ---------------------------------------------------------------------------
__global__ void detect_dtype(const void* __restrict__ h, int* __restrict__ flag) {
    if (threadIdx.x == 0 && blockIdx.x == 0) {
        const u16* us = (const u16*)h;
        int cnt = 0;
        for (int i = 0; i < 256; ++i) {
            int e8 = (us[2 * i] >> 7) & 0xFF;
            if (e8 >= 0x60 && e8 <= 0x8F) ++cnt;
        }
        *flag = (cnt >= 192) ? 1 : 0;
    }
}

// ---------------------------------------------------------------------------
// K1: fused 4-projection GEMM + CSR scatter on grid.y==4 (verbatim R16).
// ---------------------------------------------------------------------------
__global__ __launch_bounds__(256) void proj_gemm(
    const void* __restrict__ h,
    const void* __restrict__ W0, const void* __restrict__ b0,
    const void* __restrict__ W1, const void* __restrict__ b1,
    const void* __restrict__ W2, const void* __restrict__ b2,
    const void* __restrict__ W3, const void* __restrict__ b3,
    float* __restrict__ oAh, u32* __restrict__ oDB, u32* __restrict__ oEhb,
    int N, const int* __restrict__ flagp,
    const int* __restrict__ src, const int* __restrict__ dst,
    int* __restrict__ cursor, int* __restrict__ esrc, int E)
{
    if (blockIdx.y == 4) {
        int stride = gridDim.x * 256;
        for (int e = blockIdx.x * 256 + threadIdx.x; e < E; e += stride) {
            int pos = atomicAdd(&cursor[dst[e]], 1);
            esrc[pos] = src[e];
        }
        return;
    }

    const void* W; const void* bias;
    switch (blockIdx.y) {
        case 0:  W = W0; bias = b0; break;
        case 1:  W = W1; bias = b1; break;
        case 2:  W = W2; bias = b2; break;
        default: W = W3; bias = b3; break;
    }
    const int bf = *flagp;

    __shared__ float Hs[64][DIM + 4];
    __shared__ float Ws[16][DIM];

    const int t  = threadIdx.x;
    const int m0 = blockIdx.x * 64;

    if (bf) {
        for (int f = t; f < 1024; f += 256) {
            int r = f >> 4, c8 = f & 15;
            int gr = m0 + r;
            uint4 v = make_uint4(0u, 0u, 0u, 0u);
            if (gr < N) v = ((const uint4*)h)[(size_t)gr * 16 + c8];
            float* p = &Hs[r][c8 * 8];
            p[0] = bflo(v.x); p[1] = bfhi(v.x);
            p[2] = bflo(v.y); p[3] = bfhi(v.y);
            p[4] = bflo(v.z); p[5] = bfhi(v.z);
            p[6] = bflo(v.w); p[7] = bfhi(v.w);
        }
    } else {
        for (int f = t; f < 2048; f += 256) {
            int r = f >> 5, c4 = f & 31;
            int gr = m0 + r;
            float4 v = make_float4(0.f, 0.f, 0.f, 0.f);
            if (gr < N) v = ((const float4*)h)[(size_t)gr * 32 + c4];
            float* p = &Hs[r][c4 * 4];
            p[0] = v.x; p[1] = v.y; p[2] = v.z; p[3] = v.w;
        }
    }

    const int cg = t & 31;
    const int rg = t >> 5;

    float acc[8][4];
    #pragma unroll
    for (int i = 0; i < 8; ++i)
        #pragma unroll
        for (int j = 0; j < 4; ++j) acc[i][j] = 0.f;

    for (int kc = 0; kc < DIM; kc += 16) {
        __syncthreads();
        if (bf) {
            int r = t >> 4, c8 = t & 15;
            uint4 v = ((const uint4*)W)[(size_t)(kc + r) * 16 + c8];
            float* p = &Ws[r][c8 * 8];
            p[0] = bflo(v.x); p[1] = bfhi(v.x);
            p[2] = bflo(v.y); p[3] = bfhi(v.y);
            p[4] = bflo(v.z); p[5] = bfhi(v.z);
            p[6] = bflo(v.w); p[7] = bfhi(v.w);
        } else {
            for (int f = t; f < 512; f += 256) {
                int r = f >> 5, c4 = f & 31;
                float4 v = ((const float4*)W)[(size_t)(kc + r) * 32 + c4];
                float* p = &Ws[r][c4 * 4];
                p[0] = v.x; p[1] = v.y; p[2] = v.z; p[3] = v.w;
            }
        }
        __syncthreads();
        #pragma unroll
        for (int kk = 0; kk < 16; ++kk) {
            float4 w = *((const float4*)&Ws[kk][cg * 4]);
            #pragma unroll
            for (int i = 0; i < 8; ++i) {
                float hv = Hs[rg * 8 + i][kc + kk];
                acc[i][0] += hv * w.x;
                acc[i][1] += hv * w.y;
                acc[i][2] += hv * w.z;
                acc[i][3] += hv * w.w;
            }
        }
    }

    float bv[4];
    #pragma unroll
    for (int j = 0; j < 4; ++j) bv[j] = loadF(bias, cg * 4 + j, bf);

    const int y = blockIdx.y;
    #pragma unroll
    for (int i = 0; i < 8; ++i) {
        int gr = m0 + rg * 8 + i;
        if (gr < N) {
            float v0 = acc[i][0] + bv[0];
            float v1 = acc[i][1] + bv[1];
            float v2 = acc[i][2] + bv[2];
            float v3 = acc[i][3] + bv[3];
            if (y == 0) {
                ((float4*)oAh)[(size_t)gr * 32 + cg] = make_float4(v0, v1, v2, v3);
            } else {
                uint2 p;
                p.x = (u32)f2bf(v0) | ((u32)f2bf(v1) << 16);
                p.y = (u32)f2bf(v2) | ((u32)f2bf(v3) << 16);
                size_t idx;
                if (y == 1)      idx = (size_t)gr * 64 + 32 + cg;  // Bh half of DB
                else if (y == 2) idx = (size_t)gr * 64 + cg;       // Dh half of DB
                else             idx = (size_t)gr * 32 + cg;       // Ehb
                u32* base = (y == 3) ? oEhb : oDB;
                ((uint2*)base)[idx] = p;
            }
        }
    }
}

// ---------------------------------------------------------------------------
// CSR build (verbatim from passing rounds).
// ---------------------------------------------------------------------------
__global__ __launch_bounds__(256) void k_hist(const int* __restrict__ dst,
                                              int* __restrict__ deg, int E)
{
    int e = blockIdx.x * 256 + threadIdx.x;
    if (e < E) atomicAdd(&deg[dst[e]], 1);
}

__global__ __launch_bounds__(256) void k_scan1(const int* __restrict__ deg,
                                               int* __restrict__ rowstart,
                                               int* __restrict__ part, int N)
{
    __shared__ int s[256];
    int t = threadIdx.x;
    int i = blockIdx.x * 256 + t;
    int d = (i < N) ? deg[i] : 0;
    s[t] = d;
    __syncthreads();
    for (int off = 1; off < 256; off <<= 1) {
        int v = (t >= off) ? s[t - off] : 0;
        __syncthreads();
        s[t] += v;
        __syncthreads();
    }
    if (i < N) rowstart[i] = s[t] - d;
    if (t == 255) part[blockIdx.x] = s[255];
}

__global__ void k_scan2(int* __restrict__ part, int nb)
{
    __shared__ int s[256];
    int t = threadIdx.x;
    int d = (t < nb) ? part[t] : 0;
    s[t] = d;
    __syncthreads();
    for (int off = 1; off < 256; off <<= 1) {
        int v = (t >= off) ? s[t - off] : 0;
        __syncthreads();
        s[t] += v;
        __syncthreads();
    }
    if (t < nb) part[t] = s[t] - d;
}

__global__ __launch_bounds__(256) void k_scan3(int* __restrict__ rowstart,
                                               int* __restrict__ cursor,
                                               const int* __restrict__ part,
                                               int N, int E)
{
    int i = blockIdx.x * 256 + threadIdx.x;
    if (i < N) {
        int v = rowstart[i] + part[blockIdx.x];
        rowstart[i] = v;
        cursor[i] = v;
    }
    if (i == 0) rowstart[N] = E;
}

// ---------------------------------------------------------------------------
// K3: fused aggregate + e-copy, interleaved roles (verbatim R16/R14).
// ---------------------------------------------------------------------------
__global__ __launch_bounds__(256) void k_aggregate(
    const float* __restrict__ Ah, const u32* __restrict__ DB,
    const u32* __restrict__ Ehb,
    const int* __restrict__ rowstart, const int* __restrict__ esrc,
    float* __restrict__ hnew, float* __restrict__ gsum, float* __restrict__ gsq,
    int N,
    const void* __restrict__ e, void* __restrict__ dout,
    size_t nd, size_t ecount, const int* __restrict__ flagp)
{
    int t = threadIdx.x;
    int bid = blockIdx.x;
    int r3 = bid % 3;

    if (r3 == 2) {
        int bf = *flagp;
        size_t esz = bf ? 2 : 4;
        const uint4* s = (const uint4*)e;
        uint4* d = (uint4*)((char*)dout + nd * esz);
        size_t n16 = (ecount * esz) / 16;
        size_t cb = (size_t)(gridDim.x / 3);
        size_t idx = (size_t)(bid / 3) * 256 + t;
        size_t stride = cb * 256;
        for (size_t i = idx; i < n16; i += stride) d[i] = s[i];
        return;
    }

    const int abid = (bid / 3) * 2 + r3;

    int lane = t & 63;
    int wv = t >> 6;
    int nquads = (N + 3) >> 2;

    float lsum0 = 0.f, lsum1 = 0.f, lsq0 = 0.f, lsq1 = 0.f;
    for (int q = abid; q < nquads; q += AGG_BLOCKS) {
        int n = q * 4 + wv;
        if (n < N) {
            u32 ehp = Ehb[(size_t)n * 64 + lane];
            float eh0 = bflo(ehp), eh1 = bfhi(ehp);
            float2 ahp = ((const float2*)Ah)[(size_t)n * 64 + lane];
            float num0 = 0.f, den0 = 0.f, num1 = 0.f, den1 = 0.f;
            int beg = rowstart[n], end = rowstart[n + 1];
            int k = beg;
            for (; k + 4 <= end; k += 4) {
                int s0 = esrc[k], s1 = esrc[k + 1], s2 = esrc[k + 2], s3 = esrc[k + 3];
                u32 dhA = DB[(size_t)s0 * 128 + lane];
                u32 bhA = DB[(size_t)s0 * 128 + 64 + lane];
                u32 dhB = DB[(size_t)s1 * 128 + lane];
                u32 bhB = DB[(size_t)s1 * 128 + 64 + lane];
                u32 dhC = DB[(size_t)s2 * 128 + lane];
                u32 bhC = DB[(size_t)s2 * 128 + 64 + lane];
                u32 dhD = DB[(size_t)s3 * 128 + lane];
                u32 bhD = DB[(size_t)s3 * 128 + 64 + lane];
                float sA0 = 1.f / (1.f + __expf(-(bflo(dhA) + eh0)));
                float sA1 = 1.f / (1.f + __expf(-(bfhi(dhA) + eh1)));
                float sB0 = 1.f / (1.f + __expf(-(bflo(dhB) + eh0)));
                float sB1 = 1.f / (1.f + __expf(-(bfhi(dhB) + eh1)));
                float sC0 = 1.f / (1.f + __expf(-(bflo(dhC) + eh0)));
                float sC1 = 1.f / (1.f + __expf(-(bfhi(dhC) + eh1)));
                float sD0 = 1.f / (1.f + __expf(-(bflo(dhD) + eh0)));
                float sD1 = 1.f / (1.f + __expf(-(bfhi(dhD) + eh1)));
                num0 = fmaf(sA0, bflo(bhA), num0); den0 += sA0;
                num1 = fmaf(sA1, bfhi(bhA), num1); den1 += sA1;
                num0 = fmaf(sB0, bflo(bhB), num0); den0 += sB0;
                num1 = fmaf(sB1, bfhi(bhB), num1); den1 += sB1;
                num0 = fmaf(sC0, bflo(bhC), num0); den0 += sC0;
                num1 = fmaf(sC1, bfhi(bhC), num1); den1 += sC1;
                num0 = fmaf(sD0, bflo(bhD), num0); den0 += sD0;
                num1 = fmaf(sD1, bfhi(bhD), num1); den1 += sD1;
            }
            for (; k < end; ++k) {
                int s0 = esrc[k];
                u32 dh0 = DB[(size_t)s0 * 128 + lane];
                u32 bh0 = DB[(size_t)s0 * 128 + 64 + lane];
                float sa0 = 1.f / (1.f + __expf(-(bflo(dh0) + eh0)));
                float sa1 = 1.f / (1.f + __expf(-(bfhi(dh0) + eh1)));
                num0 = fmaf(sa0, bflo(bh0), num0); den0 += sa0;
                num1 = fmaf(sa1, bfhi(bh0), num1); den1 += sa1;
            }
            float x0 = ahp.x + num0 / (den0 + GATE_EPS);
            float x1 = ahp.y + num1 / (den1 + GATE_EPS);
            ((float2*)hnew)[(size_t)n * 64 + lane] = make_float2(x0, x1);
            lsum0 += x0; lsq0 += x0 * x0;
            lsum1 += x1; lsq1 += x1 * x1;
        }
    }
    __shared__ float S0[256], S1[256], Q0[256], Q1[256];
    S0[t] = lsum0; S1[t] = lsum1; Q0[t] = lsq0; Q1[t] = lsq1;
    __syncthreads();
    if (t < 64) {
        float s0 = S0[t] + S0[t + 64] + S0[t + 128] + S0[t + 192];
        float s1 = S1[t] + S1[t + 64] + S1[t + 128] + S1[t + 192];
        float q0 = Q0[t] + Q0[t + 64] + Q0[t + 128] + Q0[t + 192];
        float q1 = Q1[t] + Q1[t + 64] + Q1[t + 128] + Q1[t + 192];
        atomicAdd(&gsum[2 * t],     s0);
        atomicAdd(&gsum[2 * t + 1], s1);
        atomicAdd(&gsq[2 * t],      q0);
        atomicAdd(&gsq[2 * t + 1],  q1);
    }
}

// ---------------------------------------------------------------------------
// K4: finalize BN stats (verbatim from passing rounds).
// ---------------------------------------------------------------------------
__global__ void bn_finalize(const float* __restrict__ gsum, const float* __restrict__ gsq,
                            const void* __restrict__ gamma, const void* __restrict__ beta,
                            float* __restrict__ scale, float* __restrict__ shift,
                            int N, const int* __restrict__ flagp)
{
    int c = threadIdx.x;
    int bf = *flagp;
    if (c < DIM) {
        float invn = 1.f / (float)N;
        float mean = gsum[c] * invn;
        float var  = fmaxf(gsq[c] * invn - mean * mean, 0.f);
        float g = loadF(gamma, c, bf);
        float b = loadF(beta, c, bf);
        float sc = rsqrtf(var + BN_EPS) * g;
        scale[c] = sc;
        shift[c] = b - mean * sc;
    }
}

// ---------------------------------------------------------------------------
// K5: y = relu(x*scale + shift), vectorized (verbatim R16).
// ---------------------------------------------------------------------------
__global__ __launch_bounds__(256) void bn_apply(
    const float* __restrict__ hnew, const float* __restrict__ scale,
    const float* __restrict__ shift, void* __restrict__ outh,
    int nvec, const int* __restrict__ flagp)
{
    __shared__ float s_sc[DIM], s_sh[DIM];
    int t = threadIdx.x;
    if (t < DIM) { s_sc[t] = scale[t]; s_sh[t] = shift[t]; }
    __syncthreads();
    int bf = *flagp;

    int idx = blockIdx.x * 256 + t;
    int stride = gridDim.x * 256;
    for (int i = idx; i < nvec; i += stride) {
        float4 v = ((const float4*)hnew)[i];
        int c = (i & 31) * 4;
        float a0 = fmaxf(0.f, v.x * s_sc[c + 0] + s_sh[c + 0]);
        float a1 = fmaxf(0.f, v.y * s_sc[c + 1] + s_sh[c + 1]);
        float a2 = fmaxf(0.f, v.z * s_sc[c + 2] + s_sh[c + 2]);
        float a3 = fmaxf(0.f, v.w * s_sc[c + 3] + s_sh[c + 3]);
        if (bf) {
            uint2 o;
            o.x = (u32)f2bf(a0) | ((u32)f2bf(a1) << 16);
            o.y = (u32)f2bf(a2) | ((u32)f2bf(a3) << 16);
            ((uint2*)outh)[i] = o;
        } else {
            ((float4*)outh)[i] = make_float4(a0, a1, a2, a3);
        }
    }
}

// ---------------------------------------------------------------------------
extern "C" void kernel_launch(void* const* d_in, const int* in_sizes, int n_in,
                              void* d_out, int out_size, void* d_ws, size_t ws_size,
                              hipStream_t stream)
{
    const void* h     = d_in[0];
    const void* e     = d_in[1];
    const int*  src   = (const int*)d_in[2];
    const int*  dst   = (const int*)d_in[3];
    const void* Wa    = d_in[4];
    const void* ba    = d_in[5];
    const void* Wb    = d_in[6];
    const void* bb    = d_in[7];
    const void* Wd    = d_in[8];
    const void* bd    = d_in[9];
    const void* We    = d_in[10];
    const void* be    = d_in[11];
    const void* gamma = d_in[12];
    const void* beta  = d_in[13];

    const int N = in_sizes[0] / DIM;        // 50000
    const int E = in_sizes[2];              // 800000
    const size_t nd = (size_t)N * DIM;
    const size_t ecount = (size_t)E * DIM;

    float* ws    = (float*)d_ws;
    float* Ah    = ws;                         // nd f32
    float* hnew  = ws + nd;                    // nd f32
    u32*   DB    = (u32*)(ws + 2 * nd);        // N*128 u32 (Dh|Bh halves)
    u32*   Ehb   = (u32*)(ws + 3 * nd);        // N*64 u32 (Eh bf16 pairs)
    float* gsum  = ws + 3 * nd + nd / 2;       // 128
    float* gsq   = gsum + DIM;                 // 128
    float* scale = gsum + 2 * DIM;             // 128
    float* shift = gsum + 3 * DIM;             // 128
    int*   flag  = (int*)(gsum + 4 * DIM);     // [0]=dtype
    int*   deg      = flag + 64;               // N
    int*   rowstart = deg + N;                 // N+1
    int*   cursor   = rowstart + N + 1;        // N
    int*   part     = cursor + N;              // 256
    int*   esrc     = part + 256;              // E

    // zero BN stats + flag area, then detect_dtype writes flag[0].
    hipMemsetAsync(gsum, 0, (4 * DIM + 64) * sizeof(float), stream);
    hipMemsetAsync(deg, 0, (size_t)N * sizeof(int), stream);

    detect_dtype<<<1, 64, 0, stream>>>(h, flag);

    const int nbE = (E + 255) / 256;
    const int nbN = (N + 255) / 256;

    k_hist<<<nbE, 256, 0, stream>>>(dst, deg, E);
    k_scan1<<<nbN, 256, 0, stream>>>(deg, rowstart, part, N);
    k_scan2<<<1, 256, 0, stream>>>(part, nbN);
    k_scan3<<<nbN, 256, 0, stream>>>(rowstart, cursor, part, N, E);

    // fused: proj (y<4) + scatter (y==4)
    dim3 g1((N + 63) / 64, 5);
    proj_gemm<<<g1, 256, 0, stream>>>(h, Wa, ba, Wb, bb, Wd, bd, We, be,
                                      Ah, DB, Ehb, N, flag,
                                      src, dst, cursor, esrc, E);

    // fused: aggregate (bid%3 in {0,1}) + e-copy (bid%3 == 2), interleaved
    k_aggregate<<<3072, 256, 0, stream>>>(
        Ah, DB, Ehb, rowstart, esrc, hnew, gsum, gsq, N,
        e, d_out, nd, ecount, flag);

    bn_finalize<<<1, 128, 0, stream>>>(gsum, gsq, gamma, beta, scale, shift, N, flag);

    bn_apply<<<2048, 256, 0, stream>>>(hnew, scale, shift, d_out, (int)(nd / 4), flag);
}